// Round 2
// baseline (381.727 us; speedup 1.0000x reference)
//
#include <hip/hip_runtime.h>
#include <hip/hip_fp16.h>
#include <stdint.h>

// MaskCrossAttention: B=4, LQ=LKV=1024, C=EMBED=768, NH=12, HD=64, SCALE=0.125
// Round 1: attn kv-loop software-pipelined — one-tile-ahead register
// double-buffer of K, pos, V streams (latency-bound fix; was 517 GB/s / 6.5%).

typedef _Float16 f16;
typedef __attribute__((ext_vector_type(8))) _Float16 f16x8;
typedef __attribute__((ext_vector_type(4))) _Float16 f16x4;
typedef __attribute__((ext_vector_type(4))) float f32x4;

__device__ __forceinline__ void gload16(const void* g, void* l) {
  __builtin_amdgcn_global_load_lds(
      (__attribute__((address_space(1))) void*)(uintptr_t)g,
      (__attribute__((address_space(3))) void*)(uint32_t)(uintptr_t)l,
      16, 0, 0);
}

// f32 -> f16, 4 elems/thread
__global__ __launch_bounds__(256) void cvt_f16_kernel(const float* __restrict__ in,
                                                      f16* __restrict__ out, int n4) {
  int i = blockIdx.x * 256 + threadIdx.x;
  if (i >= n4) return;
  float4 v = reinterpret_cast<const float4*>(in)[i];
  f16x4 o = {(f16)v.x, (f16)v.y, (f16)v.z, (f16)v.w};
  reinterpret_cast<f16x4*>(out)[i] = o;
}

// W (768 x N) f32 -> Wt (N x 768) f16.  grid = (N/256)*96
__global__ __launch_bounds__(256) void transpose_w_kernel(const float* __restrict__ W,
                                                          f16* __restrict__ Wt, int N) {
  int kcb = blockIdx.x % 96;  // 96 = 768/8
  int n = (blockIdx.x / 96) * 256 + threadIdx.x;
  int k0 = kcb * 8;
  f16x8 o;
#pragma unroll
  for (int j = 0; j < 8; ++j) o[j] = (f16)W[(size_t)(k0 + j) * N + n];
  *reinterpret_cast<f16x8*>(Wt + (size_t)n * 768 + k0) = o;
}

// C = A(4096 x 768) * Bt(N x 768)^T + bias.  Tile 128x128, BK=32, 4 waves (2x2).
template <int NDIM, int EPI>
__global__ __launch_bounds__(256) void gemm_kernel(const f16* __restrict__ A,
                                                   const f16* __restrict__ Bt,
                                                   const float* __restrict__ bias,
                                                   void* __restrict__ out0,
                                                   void* __restrict__ out1) {
  constexpr int KD = 768;
  __shared__ f16 As[4 * 128 * 8];
  __shared__ f16 Bs[4 * 128 * 8];
  const int t = threadIdx.x;
  const int lane = t & 63, wid = t >> 6;
  const int bm = blockIdx.x / (NDIM / 128), bn = blockIdx.x % (NDIM / 128);
  const int m0 = bm * 128, n0 = bn * 128;
  const int wm = wid >> 1, wn = wid & 1;
  const int cr = lane & 15, grp = lane >> 4;
  f32x4 acc[4][4] = {};
  for (int k0 = 0; k0 < KD; k0 += 32) {
    __syncthreads();
#pragma unroll
    for (int it = 0; it < 2; ++it) {
      int ia = it * 256 + wid * 64 + lane;
      int kc = ia >> 7, row = ia & 127;
      gload16(A + (size_t)(m0 + row) * KD + k0 + kc * 8,
              As + (it * 256 + wid * 64) * 8);
      gload16(Bt + (size_t)(n0 + row) * KD + k0 + kc * 8,
              Bs + (it * 256 + wid * 64) * 8);
    }
    __syncthreads();
    f16x8 af[4], bf[4];
#pragma unroll
    for (int mf = 0; mf < 4; ++mf)
      af[mf] = *reinterpret_cast<const f16x8*>(As + (grp * 128 + wm * 64 + mf * 16 + cr) * 8);
#pragma unroll
    for (int nf = 0; nf < 4; ++nf)
      bf[nf] = *reinterpret_cast<const f16x8*>(Bs + (grp * 128 + wn * 64 + nf * 16 + cr) * 8);
#pragma unroll
    for (int mf = 0; mf < 4; ++mf)
#pragma unroll
      for (int nf = 0; nf < 4; ++nf)
        acc[mf][nf] = __builtin_amdgcn_mfma_f32_16x16x32_f16(af[mf], bf[nf], acc[mf][nf], 0, 0, 0);
  }
#pragma unroll
  for (int mf = 0; mf < 4; ++mf) {
    int m = m0 + wm * 64 + mf * 16 + grp * 4;  // +r per reg
    int b = m >> 10, lrow = m & 1023;
#pragma unroll
    for (int nf = 0; nf < 4; ++nf) {
      int n = n0 + wn * 64 + nf * 16 + cr;
      float bv = bias[n];
      f32x4 v = acc[mf][nf];
      if constexpr (EPI == 0) {
        int h = n >> 6, d = n & 63;
        f16* dst = (f16*)out0 + (((size_t)b * 12 + h) * 1024 + lrow) * 64 + d;
#pragma unroll
        for (int r = 0; r < 4; ++r) dst[(size_t)r * 64] = (f16)((v[r] + bv) * 0.125f);
      } else if constexpr (EPI == 1) {
        if (n < 768) {
          int h = n >> 6, d = n & 63;
          f16* dst = (f16*)out0 + (((size_t)b * 12 + h) * 1024 + lrow) * 64 + d;
#pragma unroll
          for (int r = 0; r < 4; ++r) dst[(size_t)r * 64] = (f16)(v[r] + bv);
        } else {
          int n2 = n - 768;
          int h = n2 >> 6, d = n2 & 63;
          f16x4 o;
#pragma unroll
          for (int r = 0; r < 4; ++r) o[r] = (f16)(v[r] + bv);
          *reinterpret_cast<f16x4*>((f16*)out1 + (((size_t)b * 12 + h) * 64 + d) * 1024 + lrow) = o;
        }
      } else {
        float* dst = (float*)out0 + (size_t)m * 768 + n;
#pragma unroll
        for (int r = 0; r < 4; ++r) dst[(size_t)r * 768] = v[r] + bv;
      }
    }
  }
}

// Fused flash attention, software-pipelined.
// Grid = B*NH*(LQ/64)=768 blocks, 4 independent waves, 16 q-rows/wave.
// Swapped QK^T (S^T = mfma(K,Q), q lane-local at lane&15). KVBLK=64, 16 tiles,
// fully unrolled; K/pos/V for tile t+1 issued before computing tile t so
// ~28 loads/lane stay in flight across each tile's compute (latency hiding).
__global__ __launch_bounds__(256, 2) void attn_kernel(const f16* __restrict__ Q,
                                                      const f16* __restrict__ K,
                                                      const f16* __restrict__ VT,
                                                      const float* __restrict__ pos,
                                                      const float* __restrict__ mask,
                                                      f16* __restrict__ attO) {
  const int t = threadIdx.x;
  const int lane = t & 63, wid = t >> 6;
  const int blk = blockIdx.x;
  const int bh = blk >> 4;  // b*12+h
  const int h = bh % 12, b = bh / 12;
  const int cq = lane & 15, grp = lane >> 4;
  const int q = (blk & 15) * 64 + wid * 16 + cq;
  const f16* Qp = Q + ((size_t)bh * 1024 + q) * 64 + grp * 8;
  const f16x8 qf0 = *reinterpret_cast<const f16x8*>(Qp);
  const f16x8 qf1 = *reinterpret_cast<const f16x8*>(Qp + 32);
  const f16* Kb = K + (size_t)bh * 1024 * 64;
  const f16* Vb = VT + (size_t)bh * 64 * 1024;
  const float* pb = pos + ((size_t)h * 1024 + q) * 1024;

  // double-buffered prefetch registers (indices constant after full unroll)
  f16x8 kA[2][4], kB[2][4];  // K frags: rows kv, d 0..31 / 32..63
  f32x4 ps[2][4];            // attn_pos frags
  f16x4 vf[2][16];           // V^T frags [f*4+df]

  // prologue: tile 0 loads into buffer 0
#pragma unroll
  for (int f = 0; f < 4; ++f) {
    const f16* Kp = Kb + (size_t)(f * 16 + cq) * 64 + grp * 8;
    kA[0][f] = *reinterpret_cast<const f16x8*>(Kp);
    kB[0][f] = *reinterpret_cast<const f16x8*>(Kp + 32);
    ps[0][f] = *reinterpret_cast<const f32x4*>(pb + f * 16 + grp * 4);
#pragma unroll
    for (int df = 0; df < 4; ++df)
      vf[0][f * 4 + df] = *reinterpret_cast<const f16x4*>(
          Vb + (size_t)(df * 16 + cq) * 1024 + f * 16 + grp * 4);
  }

  float m_run = -1e30f, l_run = 0.f;
  f32x4 acc[4] = {};  // O^T: acc[df][r] -> d = df*16 + grp*4 + r, col q
#pragma unroll
  for (int tile = 0; tile < 16; ++tile) {
    const int cur = tile & 1, nxt = cur ^ 1;
    // issue next tile's loads first — in flight during this tile's compute
    if (tile < 15) {
      const int kv0 = (tile + 1) * 64;
#pragma unroll
      for (int f = 0; f < 4; ++f) {
        const f16* Kp = Kb + (size_t)(kv0 + f * 16 + cq) * 64 + grp * 8;
        kA[nxt][f] = *reinterpret_cast<const f16x8*>(Kp);
        kB[nxt][f] = *reinterpret_cast<const f16x8*>(Kp + 32);
        ps[nxt][f] = *reinterpret_cast<const f32x4*>(pb + kv0 + f * 16 + grp * 4);
#pragma unroll
        for (int df = 0; df < 4; ++df)
          vf[nxt][f * 4 + df] = *reinterpret_cast<const f16x4*>(
              Vb + (size_t)(df * 16 + cq) * 1024 + kv0 + f * 16 + grp * 4);
      }
    }
    // QK^T for current tile
    f32x4 st[4];
#pragma unroll
    for (int f = 0; f < 4; ++f) {
      f32x4 z = {0.f, 0.f, 0.f, 0.f};
      z = __builtin_amdgcn_mfma_f32_16x16x32_f16(kA[cur][f], qf0, z, 0, 0, 0);
      z = __builtin_amdgcn_mfma_f32_16x16x32_f16(kB[cur][f], qf1, z, 0, 0, 0);
      st[f] = z + ps[cur][f];
    }
    // online softmax (q = lane&15 across 4 lane-groups; 2 shuffles)
    float tm = -1e30f;
#pragma unroll
    for (int f = 0; f < 4; ++f)
#pragma unroll
      for (int r = 0; r < 4; ++r) tm = fmaxf(tm, st[f][r]);
    tm = fmaxf(tm, __shfl_xor(tm, 16));
    tm = fmaxf(tm, __shfl_xor(tm, 32));
    const float m_new = fmaxf(m_run, tm);
    const float corr = __expf(m_run - m_new);
    float ls = 0.f;
    f16x4 pf[4];
#pragma unroll
    for (int f = 0; f < 4; ++f)
#pragma unroll
      for (int r = 0; r < 4; ++r) {
        float p = __expf(st[f][r] - m_new);
        ls += p;
        pf[f][r] = (f16)p;
      }
    ls += __shfl_xor(ls, 16);
    ls += __shfl_xor(ls, 32);
    l_run = l_run * corr + ls;
    m_run = m_new;
#pragma unroll
    for (int df = 0; df < 4; ++df) acc[df] *= corr;
    // PV
#pragma unroll
    for (int f = 0; f < 4; ++f)
#pragma unroll
      for (int df = 0; df < 4; ++df)
        acc[df] = __builtin_amdgcn_mfma_f32_16x16x16f16(vf[cur][f * 4 + df], pf[f], acc[df], 0, 0, 0);
  }
  const float sc = mask[b * 1024 + q] / l_run;
  f16* ob = attO + ((size_t)b * 1024 + q) * 768 + h * 64;
#pragma unroll
  for (int df = 0; df < 4; ++df) {
    f16x4 o;
#pragma unroll
    for (int r = 0; r < 4; ++r) o[r] = (f16)(acc[df][r] * sc);
    *reinterpret_cast<f16x4*>(ob + df * 16 + grp * 4) = o;
  }
}

extern "C" void kernel_launch(void* const* d_in, const int* in_sizes, int n_in,
                              void* d_out, int out_size, void* d_ws, size_t ws_size,
                              hipStream_t stream) {
  const float* Xq   = (const float*)d_in[0];
  const float* Xkv  = (const float*)d_in[1];
  const float* mask = (const float*)d_in[2];
  const float* Wq   = (const float*)d_in[3];
  const float* bq   = (const float*)d_in[4];
  const float* Wkv  = (const float*)d_in[5];
  const float* bkv  = (const float*)d_in[6];
  const float* Wp   = (const float*)d_in[7];
  const float* bp   = (const float*)d_in[8];
  const float* pos  = (const float*)d_in[9];
  float* out = (float*)d_out;
  char* ws = (char*)d_ws;
  if (ws_size < 42467328) return;  // need ~42.5 MB scratch

  f16* Xq_h  = (f16*)(ws + 0);         // 4096*768
  f16* Xkv_h = (f16*)(ws + 6291456);   // 4096*768
  f16* WqT   = (f16*)(ws + 12582912);  // 768*768
  f16* WkvT  = (f16*)(ws + 13762560);  // 1536*768
  f16* WpT   = (f16*)(ws + 16121856);  // 768*768
  f16* Qb    = (f16*)(ws + 17301504);  // (B,NH,LQ,HD)
  f16* Kb    = (f16*)(ws + 23592960);  // (B,NH,LKV,HD)
  f16* VTb   = (f16*)(ws + 29884416);  // (B,NH,HD,LKV)
  f16* attO  = (f16*)(ws + 36175872);  // (B,LQ,EMBED)

  cvt_f16_kernel<<<3072, 256, 0, stream>>>(Xq, Xq_h, 786432);
  cvt_f16_kernel<<<3072, 256, 0, stream>>>(Xkv, Xkv_h, 786432);
  transpose_w_kernel<<<3 * 96, 256, 0, stream>>>(Wq, WqT, 768);
  transpose_w_kernel<<<6 * 96, 256, 0, stream>>>(Wkv, WkvT, 1536);
  transpose_w_kernel<<<3 * 96, 256, 0, stream>>>(Wp, WpT, 768);
  gemm_kernel<768, 0><<<32 * 6, 256, 0, stream>>>(Xq_h, WqT, bq, Qb, nullptr);
  gemm_kernel<1536, 1><<<32 * 12, 256, 0, stream>>>(Xkv_h, WkvT, bkv, Kb, VTb);
  attn_kernel<<<768, 256, 0, stream>>>(Qb, Kb, VTb, pos, mask, attO);
  gemm_kernel<768, 2><<<32 * 6, 256, 0, stream>>>(attO, WpT, bp, out, nullptr);
}

// Round 3
// 157.691 us; speedup vs baseline: 2.4207x; 2.4207x over previous
//
#include <hip/hip_runtime.h>
#include <hip/hip_fp16.h>
#include <stdint.h>

// MaskCrossAttention: B=4, LQ=LKV=1024, C=EMBED=768, NH=12, HD=64, SCALE=0.125
// Round 2: attn uses LDS double-buffered K/V staging via global_load_lds
// (shared across the block's 4 waves) + register-prefetched pos frags with
// a hand-written 2-tile loop body (static indices; r1's register double-buffer
// spilled to scratch -> 200MB of local-memory traffic).

typedef _Float16 f16;
typedef __attribute__((ext_vector_type(8))) _Float16 f16x8;
typedef __attribute__((ext_vector_type(4))) _Float16 f16x4;
typedef __attribute__((ext_vector_type(4))) float f32x4;

__device__ __forceinline__ void gload16(const void* g, void* l) {
  __builtin_amdgcn_global_load_lds(
      (__attribute__((address_space(1))) void*)(uintptr_t)g,
      (__attribute__((address_space(3))) void*)(uint32_t)(uintptr_t)l,
      16, 0, 0);
}

// f32 -> f16, 4 elems/thread
__global__ __launch_bounds__(256) void cvt_f16_kernel(const float* __restrict__ in,
                                                      f16* __restrict__ out, int n4) {
  int i = blockIdx.x * 256 + threadIdx.x;
  if (i >= n4) return;
  float4 v = reinterpret_cast<const float4*>(in)[i];
  f16x4 o = {(f16)v.x, (f16)v.y, (f16)v.z, (f16)v.w};
  reinterpret_cast<f16x4*>(out)[i] = o;
}

// W (768 x N) f32 -> Wt (N x 768) f16.  grid = (N/256)*96
__global__ __launch_bounds__(256) void transpose_w_kernel(const float* __restrict__ W,
                                                          f16* __restrict__ Wt, int N) {
  int kcb = blockIdx.x % 96;  // 96 = 768/8
  int n = (blockIdx.x / 96) * 256 + threadIdx.x;
  int k0 = kcb * 8;
  f16x8 o;
#pragma unroll
  for (int j = 0; j < 8; ++j) o[j] = (f16)W[(size_t)(k0 + j) * N + n];
  *reinterpret_cast<f16x8*>(Wt + (size_t)n * 768 + k0) = o;
}

// C = A(4096 x 768) * Bt(N x 768)^T + bias.  Tile 128x128, BK=32, 4 waves (2x2).
template <int NDIM, int EPI>
__global__ __launch_bounds__(256) void gemm_kernel(const f16* __restrict__ A,
                                                   const f16* __restrict__ Bt,
                                                   const float* __restrict__ bias,
                                                   void* __restrict__ out0,
                                                   void* __restrict__ out1) {
  constexpr int KD = 768;
  __shared__ f16 As[4 * 128 * 8];
  __shared__ f16 Bs[4 * 128 * 8];
  const int t = threadIdx.x;
  const int lane = t & 63, wid = t >> 6;
  const int bm = blockIdx.x / (NDIM / 128), bn = blockIdx.x % (NDIM / 128);
  const int m0 = bm * 128, n0 = bn * 128;
  const int wm = wid >> 1, wn = wid & 1;
  const int cr = lane & 15, grp = lane >> 4;
  f32x4 acc[4][4] = {};
  for (int k0 = 0; k0 < KD; k0 += 32) {
    __syncthreads();
#pragma unroll
    for (int it = 0; it < 2; ++it) {
      int ia = it * 256 + wid * 64 + lane;
      int kc = ia >> 7, row = ia & 127;
      gload16(A + (size_t)(m0 + row) * KD + k0 + kc * 8,
              As + (it * 256 + wid * 64) * 8);
      gload16(Bt + (size_t)(n0 + row) * KD + k0 + kc * 8,
              Bs + (it * 256 + wid * 64) * 8);
    }
    __syncthreads();
    f16x8 af[4], bf[4];
#pragma unroll
    for (int mf = 0; mf < 4; ++mf)
      af[mf] = *reinterpret_cast<const f16x8*>(As + (grp * 128 + wm * 64 + mf * 16 + cr) * 8);
#pragma unroll
    for (int nf = 0; nf < 4; ++nf)
      bf[nf] = *reinterpret_cast<const f16x8*>(Bs + (grp * 128 + wn * 64 + nf * 16 + cr) * 8);
#pragma unroll
    for (int mf = 0; mf < 4; ++mf)
#pragma unroll
      for (int nf = 0; nf < 4; ++nf)
        acc[mf][nf] = __builtin_amdgcn_mfma_f32_16x16x32_f16(af[mf], bf[nf], acc[mf][nf], 0, 0, 0);
  }
#pragma unroll
  for (int mf = 0; mf < 4; ++mf) {
    int m = m0 + wm * 64 + mf * 16 + grp * 4;  // +r per reg
    int b = m >> 10, lrow = m & 1023;
#pragma unroll
    for (int nf = 0; nf < 4; ++nf) {
      int n = n0 + wn * 64 + nf * 16 + cr;
      float bv = bias[n];
      f32x4 v = acc[mf][nf];
      if constexpr (EPI == 0) {
        int h = n >> 6, d = n & 63;
        f16* dst = (f16*)out0 + (((size_t)b * 12 + h) * 1024 + lrow) * 64 + d;
#pragma unroll
        for (int r = 0; r < 4; ++r) dst[(size_t)r * 64] = (f16)((v[r] + bv) * 0.125f);
      } else if constexpr (EPI == 1) {
        if (n < 768) {
          int h = n >> 6, d = n & 63;
          f16* dst = (f16*)out0 + (((size_t)b * 12 + h) * 1024 + lrow) * 64 + d;
#pragma unroll
          for (int r = 0; r < 4; ++r) dst[(size_t)r * 64] = (f16)(v[r] + bv);
        } else {
          int n2 = n - 768;
          int h = n2 >> 6, d = n2 & 63;
          f16x4 o;
#pragma unroll
          for (int r = 0; r < 4; ++r) o[r] = (f16)(v[r] + bv);
          *reinterpret_cast<f16x4*>((f16*)out1 + (((size_t)b * 12 + h) * 64 + d) * 1024 + lrow) = o;
        }
      } else {
        float* dst = (float*)out0 + (size_t)m * 768 + n;
#pragma unroll
        for (int r = 0; r < 4; ++r) dst[(size_t)r * 768] = v[r] + bv;
      }
    }
  }
}

// Fused flash attention, LDS double-buffered.
// Grid = B*NH*(LQ/64)=768 blocks, 4 waves (16 q-rows each), KVBLK=64, 16 tiles.
// K tile [dc(8)][kv(64)][8 f16] and V^T tile [kc8(8)][d(64)][8 f16] staged via
// global_load_lds (linear dest, conflict-free frag reads); pos frags register-
// prefetched (psA/psB, static indexing). Per tile: stage(t+1) -> compute(t)
// from LDS -> vmcnt(0)+barrier.  Swapped QK^T as before.
__global__ __launch_bounds__(256) void attn_kernel(const f16* __restrict__ Q,
                                                   const f16* __restrict__ K,
                                                   const f16* __restrict__ VT,
                                                   const float* __restrict__ pos,
                                                   const float* __restrict__ mask,
                                                   f16* __restrict__ attO) {
  __shared__ f16 Ks[2][4096];  // [dc 0..7][kv 0..63][8]
  __shared__ f16 Vs[2][4096];  // [kc8 0..7][d 0..63][8]
  const int t = threadIdx.x;
  const int lane = t & 63, wid = t >> 6;
  const int blk = blockIdx.x;
  const int bh = blk >> 4;  // b*12+h
  const int h = bh % 12, b = bh / 12;
  const int cq = lane & 15, grp = lane >> 4;
  const int q = (blk & 15) * 64 + wid * 16 + cq;
  const f16* Qp = Q + ((size_t)bh * 1024 + q) * 64 + grp * 8;
  const f16x8 qf0 = *reinterpret_cast<const f16x8*>(Qp);
  const f16x8 qf1 = *reinterpret_cast<const f16x8*>(Qp + 32);
  const f16* Kb = K + (size_t)bh * 1024 * 64;
  const f16* Vb = VT + (size_t)bh * 64 * 1024;
  const float* pb = pos + ((size_t)h * 1024 + q) * 1024;

  float m_run = -1e30f, l_run = 0.f;
  f32x4 acc[4] = {};   // O^T: acc[df][r] -> d = df*16 + grp*4 + r, col q
  f32x4 psA[4], psB[4];

  auto stageKV = [&](f16* Ksb, f16* Vsb, int kv0) {
#pragma unroll
    for (int it = 0; it < 2; ++it) {
      int ci = it * 256 + t;
      int hi = ci >> 6, lo = ci & 63;
      gload16(Kb + (size_t)(kv0 + lo) * 64 + hi * 8, Ksb + ci * 8);
      gload16(Vb + (size_t)lo * 1024 + kv0 + hi * 8, Vsb + ci * 8);
    }
  };
  auto loadpos = [&](f32x4* psX, int kv0) {
#pragma unroll
    for (int f = 0; f < 4; ++f)
      psX[f] = *reinterpret_cast<const f32x4*>(pb + kv0 + f * 16 + grp * 4);
  };
  auto compute = [&](const f16* Ksb, const f16* Vsb, const f32x4* psX) {
    f32x4 st[4];
#pragma unroll
    for (int f = 0; f < 4; ++f) {
      f16x8 kf0 = *reinterpret_cast<const f16x8*>(Ksb + (grp * 64 + f * 16 + cq) * 8);
      f16x8 kf1 = *reinterpret_cast<const f16x8*>(Ksb + ((4 + grp) * 64 + f * 16 + cq) * 8);
      f32x4 z = {0.f, 0.f, 0.f, 0.f};
      z = __builtin_amdgcn_mfma_f32_16x16x32_f16(kf0, qf0, z, 0, 0, 0);
      z = __builtin_amdgcn_mfma_f32_16x16x32_f16(kf1, qf1, z, 0, 0, 0);
      st[f] = z + psX[f];
    }
    float tm = -1e30f;
#pragma unroll
    for (int f = 0; f < 4; ++f)
#pragma unroll
      for (int r = 0; r < 4; ++r) tm = fmaxf(tm, st[f][r]);
    tm = fmaxf(tm, __shfl_xor(tm, 16));
    tm = fmaxf(tm, __shfl_xor(tm, 32));
    const float m_new = fmaxf(m_run, tm);
    const float corr = __expf(m_run - m_new);
    float ls = 0.f;
    f16x4 pf[4];
#pragma unroll
    for (int f = 0; f < 4; ++f)
#pragma unroll
      for (int r = 0; r < 4; ++r) {
        float p = __expf(st[f][r] - m_new);
        ls += p;
        pf[f][r] = (f16)p;
      }
    ls += __shfl_xor(ls, 16);
    ls += __shfl_xor(ls, 32);
    l_run = l_run * corr + ls;
    m_run = m_new;
#pragma unroll
    for (int df = 0; df < 4; ++df) acc[df] *= corr;
#pragma unroll
    for (int f = 0; f < 4; ++f)
#pragma unroll
      for (int df = 0; df < 4; ++df) {
        f16x4 vf = *reinterpret_cast<const f16x4*>(
            Vsb + ((f * 2 + (grp >> 1)) * 64 + df * 16 + cq) * 8 + (grp & 1) * 4);
        acc[df] = __builtin_amdgcn_mfma_f32_16x16x16f16(vf, pf[f], acc[df], 0, 0, 0);
      }
  };

  // prologue: tile 0 into buffer 0
  stageKV(Ks[0], Vs[0], 0);
  loadpos(psA, 0);
  asm volatile("s_waitcnt vmcnt(0)" ::: "memory");
  __syncthreads();

  for (int tp = 0; tp < 8; ++tp) {
    const int te = tp * 2;
    // even tile (buffer 0, psA); stage odd tile into buffer 1
    stageKV(Ks[1], Vs[1], (te + 1) * 64);
    loadpos(psB, (te + 1) * 64);
    compute(Ks[0], Vs[0], psA);
    asm volatile("s_waitcnt vmcnt(0)" ::: "memory");
    __syncthreads();
    // odd tile (buffer 1, psB); stage next even tile into buffer 0
    if (te + 2 < 16) {
      stageKV(Ks[0], Vs[0], (te + 2) * 64);
      loadpos(psA, (te + 2) * 64);
    }
    compute(Ks[1], Vs[1], psB);
    asm volatile("s_waitcnt vmcnt(0)" ::: "memory");
    __syncthreads();
  }

  const float sc = mask[b * 1024 + q] / l_run;
  f16* ob = attO + ((size_t)b * 1024 + q) * 768 + h * 64;
#pragma unroll
  for (int df = 0; df < 4; ++df) {
    f16x4 o;
#pragma unroll
    for (int r = 0; r < 4; ++r) o[r] = (f16)(acc[df][r] * sc);
    *reinterpret_cast<f16x4*>(ob + df * 16 + grp * 4) = o;
  }
}

extern "C" void kernel_launch(void* const* d_in, const int* in_sizes, int n_in,
                              void* d_out, int out_size, void* d_ws, size_t ws_size,
                              hipStream_t stream) {
  const float* Xq   = (const float*)d_in[0];
  const float* Xkv  = (const float*)d_in[1];
  const float* mask = (const float*)d_in[2];
  const float* Wq   = (const float*)d_in[3];
  const float* bq   = (const float*)d_in[4];
  const float* Wkv  = (const float*)d_in[5];
  const float* bkv  = (const float*)d_in[6];
  const float* Wp   = (const float*)d_in[7];
  const float* bp   = (const float*)d_in[8];
  const float* pos  = (const float*)d_in[9];
  float* out = (float*)d_out;
  char* ws = (char*)d_ws;
  if (ws_size < 42467328) return;  // need ~42.5 MB scratch

  f16* Xq_h  = (f16*)(ws + 0);         // 4096*768
  f16* Xkv_h = (f16*)(ws + 6291456);   // 4096*768
  f16* WqT   = (f16*)(ws + 12582912);  // 768*768
  f16* WkvT  = (f16*)(ws + 13762560);  // 1536*768
  f16* WpT   = (f16*)(ws + 16121856);  // 768*768
  f16* Qb    = (f16*)(ws + 17301504);  // (B,NH,LQ,HD)
  f16* Kb    = (f16*)(ws + 23592960);  // (B,NH,LKV,HD)
  f16* VTb   = (f16*)(ws + 29884416);  // (B,NH,HD,LKV)
  f16* attO  = (f16*)(ws + 36175872);  // (B,LQ,EMBED)

  cvt_f16_kernel<<<3072, 256, 0, stream>>>(Xq, Xq_h, 786432);
  cvt_f16_kernel<<<3072, 256, 0, stream>>>(Xkv, Xkv_h, 786432);
  transpose_w_kernel<<<3 * 96, 256, 0, stream>>>(Wq, WqT, 768);
  transpose_w_kernel<<<6 * 96, 256, 0, stream>>>(Wkv, WkvT, 1536);
  transpose_w_kernel<<<3 * 96, 256, 0, stream>>>(Wp, WpT, 768);
  gemm_kernel<768, 0><<<32 * 6, 256, 0, stream>>>(Xq_h, WqT, bq, Qb, nullptr);
  gemm_kernel<1536, 1><<<32 * 12, 256, 0, stream>>>(Xkv_h, WkvT, bkv, Kb, VTb);
  attn_kernel<<<768, 256, 0, stream>>>(Qb, Kb, VTb, pos, mask, attO);
  gemm_kernel<768, 2><<<32 * 6, 256, 0, stream>>>(attO, WpT, bp, out, nullptr);
}